// Round 8
// baseline (1891.753 us; speedup 1.0000x reference)
//
#include <hip/hip_runtime.h>
#include <stdint.h>

static constexpr int NBLK = 512;
static constexpr int NTHR = 256;
static constexpr int NTOT = NBLK * NTHR;
static constexpr uint32_t GSZ = (uint32_t)NBLK / 64u;  // blocks per arrive sub-counter
static constexpr uint32_t INF32 = 0x7fffffffu;
static constexpr uint32_t SELBIT = 0x20000000u; // selected-into-MIS flag (in cur)
static constexpr uint32_t DEADB = 0x40000000u;  // dead marker in cur (constant)
static constexpr uint32_t MAGIC = 0x13579BDFu;

// Relaxed agent-scope atomic access: serviced at the device coherence point
// (past the non-coherent per-XCD L2s). Used for ALL cross-block-mutable P5
// state so P5 barriers need no L2 writeback/invalidate.
// NOTE (R6 lesson): verified at 512 blocks; at 2048 blocks it produced wrong
// results (fabric-queue reordering window) — do not rescale.
__device__ inline uint32_t aload(const uint32_t* p) {
  return __hip_atomic_load(p, __ATOMIC_RELAXED, __HIP_MEMORY_SCOPE_AGENT);
}
__device__ inline void astore(uint32_t* p, uint32_t v) {
  __hip_atomic_store(p, v, __ATOMIC_RELAXED, __HIP_MEMORY_SCOPE_AGENT);
}
__device__ inline void amin(uint32_t* p, uint32_t v) {  // fire-and-forget
  (void)__hip_atomic_fetch_min(p, v, __ATOMIC_RELAXED, __HIP_MEMORY_SCOPE_AGENT);
}

// Full-fence grid barrier (wb+inv) — construction/epilogue phases that
// publish NON-atomic data (proven R2 topology: 512 blocks, contention-free).
// bc layout (u32 units, one 128B cacheline per hot word):
//   sub-arrive counter g at bc[g*32], g=0..63   (block b arrives at b&63)
//   master arrive at bc[2048]; release word at bc[2080]; magic at bc[2112]
__device__ inline void gbar(uint32_t* bc, uint32_t& bk) {
  __syncthreads();
  if (threadIdx.x == 0) {
    __threadfence();   // release: drain + write back this XCD's L2
    bk++;
    uint32_t old = __hip_atomic_fetch_add(&bc[(blockIdx.x & 63u) << 5], 1u,
                                          __ATOMIC_RELAXED, __HIP_MEMORY_SCOPE_AGENT);
    if (old == bk * GSZ - 1u) {  // last of my 8-block group this round
      uint32_t m = __hip_atomic_fetch_add(&bc[2048], 1u, __ATOMIC_RELAXED,
                                          __HIP_MEMORY_SCOPE_AGENT);
      if (m == bk * 64u - 1u)    // last group overall -> release
        __hip_atomic_store(&bc[2080], bk, __ATOMIC_RELAXED, __HIP_MEMORY_SCOPE_AGENT);
    }
    uint32_t r = __hip_atomic_load(&bc[2080], __ATOMIC_RELAXED, __HIP_MEMORY_SCOPE_AGENT);
    while ((int32_t)(r - bk) < 0) {
      __builtin_amdgcn_s_sleep(4);  // ~256cy backoff
      r = __hip_atomic_load(&bc[2080], __ATOMIC_RELAXED, __HIP_MEMORY_SCOPE_AGENT);
    }
    __threadfence();   // acquire: invalidate stale L1/L2 lines
  }
  __syncthreads();
}

// Fence-LIGHT grid barrier for P5: all racy data is agent-atomic (cache-
// bypassing), so no L2 wb/inv is needed — only per-wave store drain
// (__threadfence_block == s_waitcnt) before arriving. Read-only data
// (adj/sc/rank) stays L2-resident across rounds.
__device__ inline void gbar_light(uint32_t* bc, uint32_t& bk) {
  __threadfence_block();  // drain this wave's outstanding (atomic) stores
  __syncthreads();
  if (threadIdx.x == 0) {
    bk++;
    uint32_t old = __hip_atomic_fetch_add(&bc[(blockIdx.x & 63u) << 5], 1u,
                                          __ATOMIC_RELAXED, __HIP_MEMORY_SCOPE_AGENT);
    if (old == bk * GSZ - 1u) {
      uint32_t m = __hip_atomic_fetch_add(&bc[2048], 1u, __ATOMIC_RELAXED,
                                          __HIP_MEMORY_SCOPE_AGENT);
      if (m == bk * 64u - 1u)
        __hip_atomic_store(&bc[2080], bk, __ATOMIC_RELAXED, __HIP_MEMORY_SCOPE_AGENT);
    }
    uint32_t r = __hip_atomic_load(&bc[2080], __ATOMIC_RELAXED, __HIP_MEMORY_SCOPE_AGENT);
    while ((int32_t)(r - bk) < 0) {
      __builtin_amdgcn_s_sleep(2);
      r = __hip_atomic_load(&bc[2080], __ATOMIC_RELAXED, __HIP_MEMORY_SCOPE_AGENT);
    }
  }
  __syncthreads();
}

// Hierarchical exclusive scan; out[i]=exclusive prefix, returns grand total.
template <typename F>
__device__ uint32_t grid_exscan(uint32_t L, F getv, uint32_t* __restrict__ out,
                                uint32_t* __restrict__ bsum, uint32_t* bc,
                                uint32_t& bk) {
  __shared__ uint32_t sh[NTHR];
  const uint32_t t = blockIdx.x * blockDim.x + threadIdx.x;
  const uint32_t chunk = (L + NTOT - 1) / NTOT;
  const uint32_t lo = t * chunk;
  const uint32_t hi = (lo + chunk < L) ? (lo + chunk) : L;
  uint32_t s = 0;
  for (uint32_t i = lo; i < hi; ++i) s += getv(i);
  sh[threadIdx.x] = s;
  __syncthreads();
  for (int off = 1; off < NTHR; off <<= 1) {
    uint32_t add = (threadIdx.x >= (uint32_t)off) ? sh[threadIdx.x - off] : 0u;
    __syncthreads();
    sh[threadIdx.x] += add;
    __syncthreads();
  }
  uint32_t excl_in_blk = sh[threadIdx.x] - s;
  if (threadIdx.x == NTHR - 1) bsum[blockIdx.x] = sh[NTHR - 1];
  gbar(bc, bk);
  if (blockIdx.x == 0) {
    constexpr int PER = NBLK / NTHR;  // 2
    uint32_t loc[PER];
    uint32_t ls = 0;
    for (int j = 0; j < PER; ++j) { loc[j] = bsum[threadIdx.x * PER + j]; ls += loc[j]; }
    __syncthreads();
    sh[threadIdx.x] = ls;
    __syncthreads();
    for (int off = 1; off < NTHR; off <<= 1) {
      uint32_t add = (threadIdx.x >= (uint32_t)off) ? sh[threadIdx.x - off] : 0u;
      __syncthreads();
      sh[threadIdx.x] += add;
      __syncthreads();
    }
    uint32_t run = sh[threadIdx.x] - ls;
    for (int j = 0; j < PER; ++j) { uint32_t v = loc[j]; bsum[threadIdx.x * PER + j] = run; run += v; }
    if (threadIdx.x == NTHR - 1) bsum[NBLK] = run;
  }
  gbar(bc, bk);
  uint32_t run = bsum[blockIdx.x] + excl_in_blk;
  for (uint32_t i = lo; i < hi; ++i) { uint32_t g = getv(i); out[i] = run; run += g; }
  gbar(bc, bk);
  return bsum[NBLK];
}

__global__ void __launch_bounds__(NTHR)
kmis_kernel(const float* __restrict__ x, const int* __restrict__ eidx,
            const float* __restrict__ eattr, const float* __restrict__ score,
            float* __restrict__ out, uint32_t* __restrict__ w,
            int N_, int E_, long long out_size, unsigned long long wcap) {
  const uint32_t N = (uint32_t)N_;
  const uint32_t E = (uint32_t)E_;
  const uint32_t EH = E >> 1;   // mirror-symmetric halves: eidx = [s;d | d;s]
  const uint32_t tid = blockIdx.x * blockDim.x + threadIdx.x;
  const uint32_t lane = threadIdx.x & 63u;
  uint32_t bk = 0;

  // ---- workspace layout (u32 units) ----
  uint32_t* bc     = w;                    // 2144 (tree barrier region)
  uint32_t* cnt    = bc + 2144;            // 16
  uint32_t* bsum   = cnt + 16;             // NBLK+1
  uint32_t* hist64 = bsum + NBLK + 1;      // 65536
  uint32_t* sc     = hist64 + 65536;       // 65536 + N (combined scan output)
  uint32_t* cur64  = sc + 65536 + N;       // 65536 (bucket fill cursors)
  uint32_t* deg    = cur64 + 65536;        // N
  uint32_t* ccur   = deg + N;              // N (CSR fill cursors)
  uint32_t* keys   = ccur + N;             // N
  uint32_t* rank   = keys + N;             // N
  uint32_t* cur    = rank + N;             // N: rank[|SELBIT] live, DEADB dead
  uint32_t* mis    = cur + N;              // N: 0 or rank+1 (owner-written only)
  uint32_t* blist  = mis + N;              // N (buckets; later MIS list id-order)
  uint32_t* frA    = blist + N;            // N
  uint32_t* frB    = frA + N;              // N
  uint32_t* idpos  = frB + N;              // N
  uint32_t* r2ip   = idpos + N;            // N
  uint32_t* clus   = r2ip + N;             // N (P6 output; aliased as killtag in P5)
  uint32_t* adj    = clus + N;             // E (CSR neighbor array)
  uint32_t* dyn    = adj + E;              // bitmap + wpre
  uint32_t* killtag = clus;  // P5-only: death-round tags (atomicMin-pushed).
                             // clus is written only in P6, after P5 completes.

  const int* rowA = eidx;
  const int* colA = eidx + E;

  // ---- handshake: robust barrier-cell init (ws is poisoned 0xAA) ----
  if (blockIdx.x == 0 && threadIdx.x == 0) {
    for (uint32_t g = 0; g < 64u; ++g)
      __hip_atomic_store(&bc[g << 5], 0u, __ATOMIC_RELAXED, __HIP_MEMORY_SCOPE_AGENT);
    __hip_atomic_store(&bc[2048], 0u, __ATOMIC_RELAXED, __HIP_MEMORY_SCOPE_AGENT);
    __hip_atomic_store(&bc[2080], 0u, __ATOMIC_RELAXED, __HIP_MEMORY_SCOPE_AGENT);
    __threadfence();
    __hip_atomic_store(&bc[2112], MAGIC, __ATOMIC_RELAXED, __HIP_MEMORY_SCOPE_AGENT);
  }
  if (threadIdx.x == 0) {
    while (__hip_atomic_load(&bc[2112], __ATOMIC_RELAXED, __HIP_MEMORY_SCOPE_AGENT) != MAGIC)
      __builtin_amdgcn_s_sleep(1);
    __threadfence();
  }
  __syncthreads();

  // ---- P0: init ----
  for (uint32_t i = tid; i < 65536u; i += NTOT) { hist64[i] = 0; cur64[i] = 0; }
  for (uint32_t i = tid; i < N; i += NTOT) {
    deg[i] = 0; ccur[i] = 0; mis[i] = 0; killtag[i] = INF32;
  }
  if (tid < 16) cnt[tid] = 0;
  gbar(bc, bk);

  // ---- P1: score keys + bucket histogram; CSR degree count (mirror-halved) ----
  for (uint32_t i = tid; i < N; i += NTOT) {
    uint32_t k = __float_as_uint(score[i]);  // monotone for x>=0
    keys[i] = k;
    atomicAdd(&hist64[k >> 16], 1u);
  }
  for (uint32_t e = tid; e < EH; e += NTOT) {
    atomicAdd(&deg[(uint32_t)rowA[e]], 1u);
    atomicAdd(&deg[(uint32_t)colA[e]], 1u);
  }
  for (uint32_t e = (EH << 1) + tid; e < E; e += NTOT)  // odd-E tail (empty here)
    atomicAdd(&deg[(uint32_t)rowA[e]], 1u);
  gbar(bc, bk);

  // ---- P2: combined exclusive scan (bucket starts | row_ptr+N) ----
  grid_exscan(65536u + N,
              [=](uint32_t i) { return (i < 65536u) ? hist64[i] : deg[i - 65536u]; },
              sc, bsum, bc, bk);
  // sc[b] = bucket start; sc[65536+v]-N = CSR row start; row end via v+1 (or E).

  // ---- P3: fill bucket lists + CSR adjacency (mirror-halved) ----
  for (uint32_t i = tid; i < N; i += NTOT) {
    uint32_t b = keys[i] >> 16;
    uint32_t p = sc[b] + atomicAdd(&cur64[b], 1u);
    blist[p] = i;
  }
  for (uint32_t e = tid; e < EH; e += NTOT) {
    uint32_t r = (uint32_t)rowA[e];
    uint32_t c = (uint32_t)colA[e];
    uint32_t p1 = (sc[65536u + r] - N) + atomicAdd(&ccur[r], 1u);
    adj[p1] = c;
    uint32_t p2 = (sc[65536u + c] - N) + atomicAdd(&ccur[c], 1u);
    adj[p2] = r;
  }
  for (uint32_t e = (EH << 1) + tid; e < E; e += NTOT) {  // odd-E tail
    uint32_t r = (uint32_t)rowA[e];
    uint32_t p = (sc[65536u + r] - N) + atomicAdd(&ccur[r], 1u);
    adj[p] = (uint32_t)colA[e];
  }
  gbar(bc, bk);

  // ---- P4: exact stable ranks ----
  for (uint32_t i = tid; i < N; i += NTOT) {
    uint32_t ki = keys[i];
    uint32_t b = ki >> 16;
    uint32_t s0 = sc[b], s1 = sc[b + 1];   // sc[65536] == N, safe for b=65535
    uint32_t r = s0;
    for (uint32_t j = s0; j < s1; ++j) {
      uint32_t jj = blist[j];
      uint32_t kj = keys[jj];
      r += (kj < ki || (kj == ki && jj < i)) ? 1u : 0u;
    }
    rank[i] = r;
    cur[i] = r;
  }
  gbar(bc, bk);
  // After this full fence: adj/sc/rank/keys are read-only + memory-published.
  // P5 touches cur/mis/killtag/frontier/cnt ONLY via agent atomics -> light
  // barriers, and adj/sc/rank stay L2-cached across all rounds.

  // ---- P5: PUSH-based MIS, 2 LIGHT barriers/round ----
  // Death is pushed by producers (fire-and-forget atomicMin into killtag):
  //   - v selects in round r  -> amin(killtag[u], r)   for all neighbors u
  //     (adjacent nodes can't both be live local minima, so a pushed node
  //      never also selects that round)
  //   - v dies in round r (not self-selected) -> amin(killtag[u], r+1)
  //     (1-hop-per-round infection; each node dies exactly once)
  // Phase B reads ONLY its own cur[v]/killtag[v]: die = SELBIT || kt <= r.
  // This replaces B's per-neighbor latency-bound gather scan entirely.
  // atomicMin is monotone; concurrent r+1 pushes during round r cannot flip
  // a "kt <= r" decision -> deterministic, reference-synchronous rounds.
  uint32_t* frCur = frA;
  uint32_t* frNxt = frB;
  uint32_t flen = N;
  for (uint32_t r = 0; r < 4000u; ++r) {
    uint32_t par = r & 1u;
    if (tid == 0) astore(&cnt[1 + par], 0u);
    // A: select local minima among live (gather with early break, cheap);
    //    on select: mark + push same-round death to neighbors.
    for (uint32_t i = tid; i < flen; i += NTOT) {
      uint32_t v = (r == 0) ? i : aload(&frCur[i]);
      uint32_t rv = rank[v];
      uint32_t s0 = sc[65536u + v] - N;
      uint32_t s1 = (v + 1 < N) ? (sc[65536u + v + 1] - N) : E;
      bool sel = true;
      uint32_t j = s0;
      while (sel && j + 8u <= s1) {
        uint32_t a0 = adj[j], a1 = adj[j+1], a2 = adj[j+2], a3 = adj[j+3];
        uint32_t a4 = adj[j+4], a5 = adj[j+5], a6 = adj[j+6], a7 = adj[j+7];
        uint32_t c0 = aload(&cur[a0]) & ~SELBIT, c1 = aload(&cur[a1]) & ~SELBIT;
        uint32_t c2 = aload(&cur[a2]) & ~SELBIT, c3 = aload(&cur[a3]) & ~SELBIT;
        uint32_t c4 = aload(&cur[a4]) & ~SELBIT, c5 = aload(&cur[a5]) & ~SELBIT;
        uint32_t c6 = aload(&cur[a6]) & ~SELBIT, c7 = aload(&cur[a7]) & ~SELBIT;
        uint32_t m01 = c0 < c1 ? c0 : c1, m23 = c2 < c3 ? c2 : c3;
        uint32_t m45 = c4 < c5 ? c4 : c5, m67 = c6 < c7 ? c6 : c7;
        uint32_t m03 = m01 < m23 ? m01 : m23, m47 = m45 < m67 ? m45 : m67;
        uint32_t m = m03 < m47 ? m03 : m47;
        if (m < rv) sel = false;  // dead == DEADB > ranks (SELBIT masked off)
        j += 8u;
      }
      while (sel && j < s1) {
        if ((aload(&cur[adj[j]]) & ~SELBIT) < rv) sel = false;
        ++j;
      }
      if (sel) {
        astore(&mis[v], rv + 1u);
        astore(&cur[v], rv | SELBIT);
        for (uint32_t q = s0; q < s1; ++q) amin(&killtag[adj[q]], r);
      }
    }
    gbar_light(bc, bk);
    // B: self-check only; dying non-MIS nodes push infection (r+1).
    uint32_t fpad = ((flen + NTOT - 1) / NTOT) * NTOT;
    for (uint32_t i = tid; i < fpad; i += NTOT) {
      bool valid = i < flen;
      uint32_t v = 0;
      bool die = false;
      if (valid) {
        v = (r == 0) ? i : aload(&frCur[i]);
        uint32_t cv = aload(&cur[v]);
        uint32_t kt = aload(&killtag[v]);   // independent loads, both in flight
        bool self_sel = (cv & SELBIT) != 0u;
        die = self_sel || (kt <= r);
        if (die) {
          astore(&cur[v], DEADB);
          if (!self_sel) {  // MIS members already pushed r (< r+1) in A
            uint32_t s0 = sc[65536u + v] - N;
            uint32_t s1 = (v + 1 < N) ? (sc[65536u + v + 1] - N) : E;
            for (uint32_t q = s0; q < s1; ++q) amin(&killtag[adj[q]], r + 1u);
          }
        }
      }
      bool surv = valid && !die;
      uint64_t mb = __ballot(surv);
      if (mb) {
        uint32_t leader = (uint32_t)__ffsll((unsigned long long)mb) - 1u;
        uint32_t base = 0;
        if (lane == leader) base = atomicAdd(&cnt[1 + par], (uint32_t)__popcll(mb));
        base = (uint32_t)__shfl((int)base, (int)leader);
        if (surv) {
          uint32_t off = (uint32_t)__popcll(mb & ((1ull << lane) - 1ull));
          astore(&frNxt[base + off], v);
        }
      }
    }
    gbar_light(bc, bk);
    flen = aload(&cnt[1 + par]);
    uint32_t* t2 = frCur; frCur = frNxt; frNxt = t2;
    if (flen == 0) break;
  }

  // ---- P6: cluster assignment (gather, atomic-free) ----
  // grid_exscan opens with a FULL gbar (inv) -> plain reads of mis/cur are
  // fresh (P5's atomic stores bypassed caches; no stale lines exist).
  // clus overwrites the killtag region from here on.
  uint32_t M = grid_exscan(N, [=](uint32_t i) { return mis[i] ? 1u : 0u; },
                           idpos, bsum, bc, bk);
  for (uint32_t v = tid; v < N; v += NTOT) {
    if (mis[v]) {
      r2ip[rank[v]] = idpos[v];
      blist[idpos[v]] = v;  // MIS nodes in id order
      atomicMax(&cnt[4], rank[v]);
    }
  }
  gbar(bc, bk);
  {
    uint32_t maxrank = cnt[4];
    for (uint32_t v = tid; v < N; v += NTOT) {
      uint32_t mv = mis[v] ? rank[v] : INF32;
      uint32_t s0 = sc[65536u + v] - N;
      uint32_t s1 = (v + 1 < N) ? (sc[65536u + v + 1] - N) : E;
      uint32_t j = s0;
      for (; j + 4u <= s1; j += 4u) {  // mis[u] = rank+1: single indep gather
        uint32_t m0 = mis[adj[j]], m1 = mis[adj[j+1]];
        uint32_t m2 = mis[adj[j+2]], m3 = mis[adj[j+3]];
        if (m0) { uint32_t ru = m0 - 1u; if (ru < mv) mv = ru; }
        if (m1) { uint32_t ru = m1 - 1u; if (ru < mv) mv = ru; }
        if (m2) { uint32_t ru = m2 - 1u; if (ru < mv) mv = ru; }
        if (m3) { uint32_t ru = m3 - 1u; if (ru < mv) mv = ru; }
      }
      for (; j < s1; ++j) {
        uint32_t m0 = mis[adj[j]];
        if (m0) { uint32_t ru = m0 - 1u; if (ru < mv) mv = ru; }
      }
      clus[v] = r2ip[(mv == INF32) ? maxrank : mv];  // orphan: clamped OOB gather
    }
  }
  gbar(bc, bk);

  // ---- P7: coarse edges (unique off-diagonal pairs, lexicographic) ----
  // Mirror halving: half-edge (r,c) -> coarse (a,b) AND (b,a); identical key
  // set and attr sums as full-list processing, half the reads and gathers.
  uint64_t M2 = (uint64_t)M * (uint64_t)M;
  uint32_t nwords = (uint32_t)((M2 + 31) >> 5);
  uint32_t* bitmap = dyn;
  uint32_t* wpre = bitmap + nwords;
  bool wsok = ((uint64_t)(dyn - w) + 2ull * nwords) <= (uint64_t)wcap;
  if (wsok) {
    for (uint32_t i = tid; i < nwords; i += NTOT) bitmap[i] = 0;
    gbar(bc, bk);
    for (uint32_t e = tid; e < EH; e += NTOT) {
      uint32_t a = clus[(uint32_t)rowA[e]], b = clus[(uint32_t)colA[e]];
      if (a != b) {
        uint32_t k1 = a * M + b;
        uint32_t k2 = b * M + a;
        atomicOr(&bitmap[k1 >> 5], 1u << (k1 & 31u));
        atomicOr(&bitmap[k2 >> 5], 1u << (k2 & 31u));
      }
    }
    for (uint32_t e = (EH << 1) + tid; e < E; e += NTOT) {  // odd-E tail
      uint32_t a = clus[(uint32_t)rowA[e]], b = clus[(uint32_t)colA[e]];
      if (a != b) {
        uint32_t key = a * M + b;
        atomicOr(&bitmap[key >> 5], 1u << (key & 31u));
      }
    }
    gbar(bc, bk);
    uint32_t nk = grid_exscan(
        nwords, [=](uint32_t i) { return (uint32_t)__popc(bitmap[i]); }, wpre,
        bsum, bc, bk);
    uint64_t oEI = (uint64_t)M * 128ull;
    uint64_t oEA = oEI + 2ull * nk;
    uint64_t oCL = oEA + nk;
    uint64_t oMIS = oCL + N;
    uint64_t oSC = oMIS + N;
    bool fits = (oSC + N) <= (uint64_t)out_size;
    if (fits) {
      for (uint32_t i = tid; i < nk; i += NTOT) out[oEA + i] = 0.0f;
      for (uint32_t wd = tid; wd < nwords; wd += NTOT) {
        uint32_t bits = bitmap[wd];
        uint32_t slot = wpre[wd];
        while (bits) {
          uint32_t bpos = (uint32_t)__ffs(bits) - 1u;
          bits &= bits - 1u;
          uint32_t key = (wd << 5) + bpos;
          uint32_t aa = key / M;
          uint32_t bb = key - aa * M;
          out[oEI + slot] = (float)aa;
          out[oEI + (uint64_t)nk + slot] = (float)bb;
          slot++;
        }
      }
      gbar(bc, bk);
      for (uint32_t e = tid; e < EH; e += NTOT) {
        uint32_t a = clus[(uint32_t)rowA[e]], b = clus[(uint32_t)colA[e]];
        if (a != b) {
          float wv = eattr[e];   // eattr[e + EH] == eattr[e] by construction
          uint32_t k1 = a * M + b;
          uint32_t wd1 = k1 >> 5, bit1 = k1 & 31u;
          uint32_t s1_ = wpre[wd1] + (uint32_t)__popc(bitmap[wd1] & ((1u << bit1) - 1u));
          atomicAdd(&out[oEA + s1_], wv);
          uint32_t k2 = b * M + a;
          uint32_t wd2 = k2 >> 5, bit2 = k2 & 31u;
          uint32_t s2_ = wpre[wd2] + (uint32_t)__popc(bitmap[wd2] & ((1u << bit2) - 1u));
          atomicAdd(&out[oEA + s2_], wv);
        }
      }
      for (uint32_t e = (EH << 1) + tid; e < E; e += NTOT) {  // odd-E tail
        uint32_t a = clus[(uint32_t)rowA[e]], b = clus[(uint32_t)colA[e]];
        if (a != b) {
          uint32_t key = a * M + b;
          uint32_t wd = key >> 5, bit = key & 31u;
          uint32_t slot = wpre[wd] + (uint32_t)__popc(bitmap[wd] & ((1u << bit) - 1u));
          atomicAdd(&out[oEA + slot], eattr[e]);
        }
      }
      // x gather (float4-vectorized), MIS rows in id order
      const float4* x4 = (const float4*)x;
      float4* o4 = (float4*)out;
      uint32_t xtot = M * 32u;
      for (uint32_t i = tid; i < xtot; i += NTOT) {
        uint32_t row = i >> 5;
        o4[i] = x4[((uint64_t)blist[row] << 5) + (i & 31u)];
      }
      for (uint32_t v = tid; v < N; v += NTOT) {
        out[oCL + v] = (float)clus[v];
        out[oMIS + v] = mis[v] ? 1.0f : 0.0f;
        out[oSC + v] = score[v];
      }
    }
  }
}

extern "C" void kernel_launch(void* const* d_in, const int* in_sizes, int n_in,
                              void* d_out, int out_size, void* d_ws, size_t ws_size,
                              hipStream_t stream) {
  (void)n_in;
  const float* x = (const float*)d_in[0];
  const int* eidx = (const int*)d_in[1];
  const float* eattr = (const float*)d_in[2];
  const float* score = (const float*)d_in[3];
  float* out = (float*)d_out;
  uint32_t* w = (uint32_t*)d_ws;
  int N = in_sizes[3];
  int E = in_sizes[2];
  long long osz = (long long)out_size;
  unsigned long long wcap = (unsigned long long)(ws_size / 4);
  void* args[] = {&x, &eidx, &eattr, &score, &out, &w, &N, &E, &osz, &wcap};
  hipLaunchCooperativeKernel((void*)kmis_kernel, dim3(NBLK), dim3(NTHR), args, 0,
                             stream);
}

// Round 9
// 1569.938 us; speedup vs baseline: 1.2050x; 1.2050x over previous
//
#include <hip/hip_runtime.h>
#include <stdint.h>

static constexpr int NBLK = 512;
static constexpr int NTHR = 256;
static constexpr int NTOT = NBLK * NTHR;
static constexpr uint32_t GSZ = (uint32_t)NBLK / 64u;  // blocks per arrive sub-counter
static constexpr uint32_t INF32 = 0x7fffffffu;
static constexpr uint32_t SELBIT = 0x20000000u; // selected-into-MIS flag (in cur)
static constexpr uint32_t DEADB = 0x40000000u;  // death tag base: DEADB + round
static constexpr uint32_t MAGIC = 0x13579BDFu;

// Relaxed agent-scope atomic access: serviced at the device coherence point
// (past the non-coherent per-XCD L2s). Data that flows ONLY through this path
// needs no L2 writeback/invalidate at barriers -> light barriers suffice.
// NOTE (R6 lesson): verified at 512 blocks; at 2048 blocks it produced wrong
// results (fabric-queue reordering window) — do not rescale.
__device__ inline uint32_t aload(const uint32_t* p) {
  return __hip_atomic_load(p, __ATOMIC_RELAXED, __HIP_MEMORY_SCOPE_AGENT);
}
__device__ inline void astore(uint32_t* p, uint32_t v) {
  __hip_atomic_store(p, v, __ATOMIC_RELAXED, __HIP_MEMORY_SCOPE_AGENT);
}

// Full-fence grid barrier (wb+inv) — ONLY where bulk plain-written data must
// be published for cached plain reads (scan outputs, adj/rank/clus tables).
// bc layout (u32 units, one 128B cacheline per hot word):
//   sub-arrive counter g at bc[g*32], g=0..63   (block b arrives at b&63)
//   master arrive at bc[2048]; release word at bc[2080]; magic at bc[2112]
__device__ inline void gbar(uint32_t* bc, uint32_t& bk) {
  __syncthreads();
  if (threadIdx.x == 0) {
    __threadfence();   // release: drain + write back this XCD's L2
    bk++;
    uint32_t old = __hip_atomic_fetch_add(&bc[(blockIdx.x & 63u) << 5], 1u,
                                          __ATOMIC_RELAXED, __HIP_MEMORY_SCOPE_AGENT);
    if (old == bk * GSZ - 1u) {  // last of my 8-block group this round
      uint32_t m = __hip_atomic_fetch_add(&bc[2048], 1u, __ATOMIC_RELAXED,
                                          __HIP_MEMORY_SCOPE_AGENT);
      if (m == bk * 64u - 1u)    // last group overall -> release
        __hip_atomic_store(&bc[2080], bk, __ATOMIC_RELAXED, __HIP_MEMORY_SCOPE_AGENT);
    }
    uint32_t r = __hip_atomic_load(&bc[2080], __ATOMIC_RELAXED, __HIP_MEMORY_SCOPE_AGENT);
    while ((int32_t)(r - bk) < 0) {
      __builtin_amdgcn_s_sleep(4);  // ~256cy backoff
      r = __hip_atomic_load(&bc[2080], __ATOMIC_RELAXED, __HIP_MEMORY_SCOPE_AGENT);
    }
    __threadfence();   // acquire: invalidate stale L1/L2 lines
  }
  __syncthreads();
}

// Fence-LIGHT grid barrier: for phases whose cross-block-mutable data is all
// agent-atomic (cache-bypassing) — no L2 wb/inv; __syncthreads' implicit
// store-drain + arrive/release ordering is sufficient. Read-only cached data
// (adj/sc/rank/eidx) stays L2-resident across these barriers.
__device__ inline void gbar_light(uint32_t* bc, uint32_t& bk) {
  __threadfence_block();  // drain this wave's outstanding (atomic) stores
  __syncthreads();
  if (threadIdx.x == 0) {
    bk++;
    uint32_t old = __hip_atomic_fetch_add(&bc[(blockIdx.x & 63u) << 5], 1u,
                                          __ATOMIC_RELAXED, __HIP_MEMORY_SCOPE_AGENT);
    if (old == bk * GSZ - 1u) {
      uint32_t m = __hip_atomic_fetch_add(&bc[2048], 1u, __ATOMIC_RELAXED,
                                          __HIP_MEMORY_SCOPE_AGENT);
      if (m == bk * 64u - 1u)
        __hip_atomic_store(&bc[2080], bk, __ATOMIC_RELAXED, __HIP_MEMORY_SCOPE_AGENT);
    }
    uint32_t r = __hip_atomic_load(&bc[2080], __ATOMIC_RELAXED, __HIP_MEMORY_SCOPE_AGENT);
    while ((int32_t)(r - bk) < 0) {
      __builtin_amdgcn_s_sleep(2);
      r = __hip_atomic_load(&bc[2080], __ATOMIC_RELAXED, __HIP_MEMORY_SCOPE_AGENT);
    }
  }
  __syncthreads();
}

// Hierarchical exclusive scan; out[i]=exclusive prefix, returns grand total.
// bsum travels via agent atomics -> internal barriers are LIGHT; only the
// final barrier is FULL (publishes plain-written out[] for cached reads).
// getv sources must be L2-clean (atomic-written or already-published) —
// holds for every call site here.
template <typename F>
__device__ uint32_t grid_exscan(uint32_t L, F getv, uint32_t* __restrict__ out,
                                uint32_t* __restrict__ bsum, uint32_t* bc,
                                uint32_t& bk) {
  __shared__ uint32_t sh[NTHR];
  const uint32_t t = blockIdx.x * blockDim.x + threadIdx.x;
  const uint32_t chunk = (L + NTOT - 1) / NTOT;
  const uint32_t lo = t * chunk;
  const uint32_t hi = (lo + chunk < L) ? (lo + chunk) : L;
  uint32_t s = 0;
  for (uint32_t i = lo; i < hi; ++i) s += getv(i);
  sh[threadIdx.x] = s;
  __syncthreads();
  for (int off = 1; off < NTHR; off <<= 1) {
    uint32_t add = (threadIdx.x >= (uint32_t)off) ? sh[threadIdx.x - off] : 0u;
    __syncthreads();
    sh[threadIdx.x] += add;
    __syncthreads();
  }
  uint32_t excl_in_blk = sh[threadIdx.x] - s;
  if (threadIdx.x == NTHR - 1) astore(&bsum[blockIdx.x], sh[NTHR - 1]);
  gbar_light(bc, bk);
  if (blockIdx.x == 0) {
    constexpr int PER = NBLK / NTHR;  // 2
    uint32_t loc[PER];
    uint32_t ls = 0;
    for (int j = 0; j < PER; ++j) { loc[j] = aload(&bsum[threadIdx.x * PER + j]); ls += loc[j]; }
    __syncthreads();
    sh[threadIdx.x] = ls;
    __syncthreads();
    for (int off = 1; off < NTHR; off <<= 1) {
      uint32_t add = (threadIdx.x >= (uint32_t)off) ? sh[threadIdx.x - off] : 0u;
      __syncthreads();
      sh[threadIdx.x] += add;
      __syncthreads();
    }
    uint32_t run = sh[threadIdx.x] - ls;
    for (int j = 0; j < PER; ++j) { uint32_t v = loc[j]; astore(&bsum[threadIdx.x * PER + j], run); run += v; }
    if (threadIdx.x == NTHR - 1) astore(&bsum[NBLK], run);
  }
  gbar_light(bc, bk);
  uint32_t run = aload(&bsum[blockIdx.x]) + excl_in_blk;
  for (uint32_t i = lo; i < hi; ++i) { uint32_t g = getv(i); out[i] = run; run += g; }
  gbar(bc, bk);   // FULL: publish out[] (plain) for all consumers
  return aload(&bsum[NBLK]);
}

__global__ void __launch_bounds__(NTHR)
kmis_kernel(const float* __restrict__ x, const int* __restrict__ eidx,
            const float* __restrict__ eattr, const float* __restrict__ score,
            float* __restrict__ out, uint32_t* __restrict__ w,
            int N_, int E_, long long out_size, unsigned long long wcap) {
  const uint32_t N = (uint32_t)N_;
  const uint32_t E = (uint32_t)E_;
  const uint32_t EH = E >> 1;   // mirror-symmetric halves: eidx = [s;d | d;s]
  const uint32_t tid = blockIdx.x * blockDim.x + threadIdx.x;
  const uint32_t lane = threadIdx.x & 63u;
  uint32_t bk = 0;

  // ---- workspace layout (u32 units) ----
  uint32_t* bc     = w;                    // 2144 (tree barrier region)
  uint32_t* cnt    = bc + 2144;            // 16
  uint32_t* bsum   = cnt + 16;             // NBLK+1
  uint32_t* hist64 = bsum + NBLK + 1;      // 65536
  uint32_t* sc     = hist64 + 65536;       // 65536 + N (combined scan output)
  uint32_t* cur64  = sc + 65536 + N;       // 65536 (bucket fill cursors)
  uint32_t* deg    = cur64 + 65536;        // N
  uint32_t* ccur   = deg + N;              // N (CSR fill cursors)
  uint32_t* keys   = ccur + N;             // N
  uint32_t* rank   = keys + N;             // N
  uint32_t* cur    = rank + N;             // N: rank[|SELBIT] live, DEADB+round dead
  uint32_t* mis    = cur + N;              // N: 0 or rank+1 (owner-written only)
  uint32_t* blist  = mis + N;              // N (buckets; later MIS list id-order)
  uint32_t* frA    = blist + N;            // N
  uint32_t* frB    = frA + N;              // N
  uint32_t* idpos  = frB + N;              // N
  uint32_t* r2ip   = idpos + N;            // N
  uint32_t* clus   = r2ip + N;             // N
  uint32_t* adj    = clus + N;             // E (CSR neighbor array)
  uint32_t* dyn    = adj + E;              // bitmap + wpre

  const int* rowA = eidx;
  const int* colA = eidx + E;

  // ---- handshake: robust barrier-cell init (ws is poisoned 0xAA) ----
  if (blockIdx.x == 0 && threadIdx.x == 0) {
    for (uint32_t g = 0; g < 64u; ++g)
      __hip_atomic_store(&bc[g << 5], 0u, __ATOMIC_RELAXED, __HIP_MEMORY_SCOPE_AGENT);
    __hip_atomic_store(&bc[2048], 0u, __ATOMIC_RELAXED, __HIP_MEMORY_SCOPE_AGENT);
    __hip_atomic_store(&bc[2080], 0u, __ATOMIC_RELAXED, __HIP_MEMORY_SCOPE_AGENT);
    __threadfence();
    __hip_atomic_store(&bc[2112], MAGIC, __ATOMIC_RELAXED, __HIP_MEMORY_SCOPE_AGENT);
  }
  if (threadIdx.x == 0) {
    while (__hip_atomic_load(&bc[2112], __ATOMIC_RELAXED, __HIP_MEMORY_SCOPE_AGENT) != MAGIC)
      __builtin_amdgcn_s_sleep(1);
    __threadfence();
  }
  __syncthreads();

  // ---- P0: init via astore (no dirty L2 lines -> light barrier suffices;
  //      memory-side RMWs in P1 then read true zeros from memory) ----
  for (uint32_t i = tid; i < 65536u; i += NTOT) { astore(&hist64[i], 0u); astore(&cur64[i], 0u); }
  for (uint32_t i = tid; i < N; i += NTOT) {
    astore(&deg[i], 0u); astore(&ccur[i], 0u); astore(&mis[i], 0u);
  }
  if (tid < 16) astore(&cnt[tid], 0u);
  gbar_light(bc, bk);

  // ---- P1: score keys + bucket histogram; CSR degree count (mirror-halved).
  //      Outputs are all memory-side RMWs; keys (plain) is published by the
  //      P2 scan's final FULL barrier before anyone reads it. -> light. ----
  for (uint32_t i = tid; i < N; i += NTOT) {
    uint32_t k = __float_as_uint(score[i]);  // monotone for x>=0
    keys[i] = k;
    atomicAdd(&hist64[k >> 16], 1u);
  }
  for (uint32_t e = tid; e < EH; e += NTOT) {
    atomicAdd(&deg[(uint32_t)rowA[e]], 1u);
    atomicAdd(&deg[(uint32_t)colA[e]], 1u);
  }
  for (uint32_t e = (EH << 1) + tid; e < E; e += NTOT)  // odd-E tail (empty here)
    atomicAdd(&deg[(uint32_t)rowA[e]], 1u);
  gbar_light(bc, bk);

  // ---- P2: combined exclusive scan (bucket starts | row_ptr+N) ----
  // hist64/deg were never plain-written since the last invalidate -> plain
  // reads inside the scan fetch fresh memory-side values. Ends with FULL.
  grid_exscan(65536u + N,
              [=](uint32_t i) { return (i < 65536u) ? hist64[i] : deg[i - 65536u]; },
              sc, bsum, bc, bk);
  // sc[b] = bucket start; sc[65536+v]-N = CSR row start; row end via v+1 (or E).

  // ---- P3: fill bucket lists + CSR adjacency (mirror-halved) ----
  for (uint32_t i = tid; i < N; i += NTOT) {
    uint32_t b = keys[i] >> 16;
    uint32_t p = sc[b] + atomicAdd(&cur64[b], 1u);
    blist[p] = i;
  }
  for (uint32_t e = tid; e < EH; e += NTOT) {
    uint32_t r = (uint32_t)rowA[e];
    uint32_t c = (uint32_t)colA[e];
    uint32_t p1 = (sc[65536u + r] - N) + atomicAdd(&ccur[r], 1u);
    adj[p1] = c;
    uint32_t p2 = (sc[65536u + c] - N) + atomicAdd(&ccur[c], 1u);
    adj[p2] = r;
  }
  for (uint32_t e = (EH << 1) + tid; e < E; e += NTOT) {  // odd-E tail
    uint32_t r = (uint32_t)rowA[e];
    uint32_t p = (sc[65536u + r] - N) + atomicAdd(&ccur[r], 1u);
    adj[p] = (uint32_t)colA[e];
  }
  gbar(bc, bk);  // FULL: publish adj/blist (plain, bulk, read-cached later)

  // ---- P4: exact stable ranks ----
  for (uint32_t i = tid; i < N; i += NTOT) {
    uint32_t ki = keys[i];
    uint32_t b = ki >> 16;
    uint32_t s0 = sc[b], s1 = sc[b + 1];   // sc[65536] == N, safe for b=65535
    uint32_t r = s0;
    for (uint32_t j = s0; j < s1; ++j) {
      uint32_t jj = blist[j];
      uint32_t kj = keys[jj];
      r += (kj < ki || (kj == ki && jj < i)) ? 1u : 0u;
    }
    rank[i] = r;
    cur[i] = r;
  }
  gbar(bc, bk);  // FULL: publish rank (cached) + cur initial state
  // After this fence: adj/sc/rank/keys read-only + published. P5 touches
  // cur/mis/frontier/cnt ONLY via agent atomics -> light barriers, and
  // adj/sc/rank stay L2-resident across all rounds.

  // ---- P5: node-centric MIS, 2 LIGHT barriers/round, frontier-compacted ----
  // cur[] encodes everything cross-block: rank (live), rank|SELBIT (selected),
  // DEADB+r (dead), DEADB|SELBIT+r (dead MIS member). Decisions are invariant
  // under the only concurrent transitions -> deterministic phases.
  // Inner loops batch 8 neighbors: coalesced adj loads then 8 INDEPENDENT
  // coherent cur gathers in flight. (R8 lesson: pull with early break beats
  // push-to-neighbors — pushes cost degree-proportional RMWs, +9%.)
  uint32_t* frCur = frA;
  uint32_t* frNxt = frB;
  uint32_t flen = N;
  for (uint32_t r = 0; r < 4000u; ++r) {
    uint32_t par = r & 1u;
    if (tid == 0) astore(&cnt[1 + par], 0u);
    // A: select local minima among live (reads cur, writes own mis/cur-SELBIT)
    for (uint32_t i = tid; i < flen; i += NTOT) {
      uint32_t v = (r == 0) ? i : aload(&frCur[i]);
      uint32_t rv = rank[v];
      uint32_t s0 = sc[65536u + v] - N;
      uint32_t s1 = (v + 1 < N) ? (sc[65536u + v + 1] - N) : E;
      bool sel = true;
      uint32_t j = s0;
      while (sel && j + 8u <= s1) {
        uint32_t a0 = adj[j], a1 = adj[j+1], a2 = adj[j+2], a3 = adj[j+3];
        uint32_t a4 = adj[j+4], a5 = adj[j+5], a6 = adj[j+6], a7 = adj[j+7];
        uint32_t c0 = aload(&cur[a0]) & ~SELBIT, c1 = aload(&cur[a1]) & ~SELBIT;
        uint32_t c2 = aload(&cur[a2]) & ~SELBIT, c3 = aload(&cur[a3]) & ~SELBIT;
        uint32_t c4 = aload(&cur[a4]) & ~SELBIT, c5 = aload(&cur[a5]) & ~SELBIT;
        uint32_t c6 = aload(&cur[a6]) & ~SELBIT, c7 = aload(&cur[a7]) & ~SELBIT;
        uint32_t m01 = c0 < c1 ? c0 : c1, m23 = c2 < c3 ? c2 : c3;
        uint32_t m45 = c4 < c5 ? c4 : c5, m67 = c6 < c7 ? c6 : c7;
        uint32_t m03 = m01 < m23 ? m01 : m23, m47 = m45 < m67 ? m45 : m67;
        uint32_t m = m03 < m47 ? m03 : m47;
        if (m < rv) sel = false;  // dead >= DEADB > ranks (SELBIT masked off)
        j += 8u;
      }
      while (sel && j < s1) {
        if ((aload(&cur[adj[j]]) & ~SELBIT) < rv) sel = false;
        ++j;
      }
      if (sel) { astore(&mis[v], rv + 1u); astore(&cur[v], rv | SELBIT); }
    }
    gbar_light(bc, bk);
    // B: die if self-selected, neighbor-MIS (SELBIT, any round), or neighbor
    // dead BEFORE this round (tag < r). Single coherent gather per neighbor.
    uint32_t fpad = ((flen + NTOT - 1) / NTOT) * NTOT;
    for (uint32_t i = tid; i < fpad; i += NTOT) {
      bool valid = i < flen;
      uint32_t v = 0;
      bool die = false;
      bool self_sel = false;
      if (valid) {
        v = (r == 0) ? i : aload(&frCur[i]);
        self_sel = (aload(&cur[v]) & SELBIT) != 0u;
        die = self_sel;
        if (!die) {
          uint32_t s0 = sc[65536u + v] - N;
          uint32_t s1 = (v + 1 < N) ? (sc[65536u + v + 1] - N) : E;
          uint32_t j = s0;
          while (!die && j + 8u <= s1) {
            uint32_t a0 = adj[j], a1 = adj[j+1], a2 = adj[j+2], a3 = adj[j+3];
            uint32_t a4 = adj[j+4], a5 = adj[j+5], a6 = adj[j+6], a7 = adj[j+7];
            uint32_t c0 = aload(&cur[a0]), c1 = aload(&cur[a1]);
            uint32_t c2 = aload(&cur[a2]), c3 = aload(&cur[a3]);
            uint32_t c4 = aload(&cur[a4]), c5 = aload(&cur[a5]);
            uint32_t c6 = aload(&cur[a6]), c7 = aload(&cur[a7]);
            uint32_t b0 = (c0 & SELBIT) | (((c0 - DEADB) < r) ? 1u : 0u);
            uint32_t b1 = (c1 & SELBIT) | (((c1 - DEADB) < r) ? 1u : 0u);
            uint32_t b2 = (c2 & SELBIT) | (((c2 - DEADB) < r) ? 1u : 0u);
            uint32_t b3 = (c3 & SELBIT) | (((c3 - DEADB) < r) ? 1u : 0u);
            uint32_t b4 = (c4 & SELBIT) | (((c4 - DEADB) < r) ? 1u : 0u);
            uint32_t b5 = (c5 & SELBIT) | (((c5 - DEADB) < r) ? 1u : 0u);
            uint32_t b6 = (c6 & SELBIT) | (((c6 - DEADB) < r) ? 1u : 0u);
            uint32_t b7 = (c7 & SELBIT) | (((c7 - DEADB) < r) ? 1u : 0u);
            if ((b0 | b1 | b2 | b3 | b4 | b5 | b6 | b7) != 0u) die = true;
            j += 8u;
          }
          while (!die && j < s1) {
            uint32_t c = aload(&cur[adj[j]]);
            if ((c & SELBIT) || (c - DEADB) < r) die = true;
            ++j;
          }
        }
        if (die) astore(&cur[v], (DEADB + r) | (self_sel ? SELBIT : 0u));
      }
      bool surv = valid && !die;
      uint64_t mb = __ballot(surv);
      if (mb) {
        uint32_t leader = (uint32_t)__ffsll((unsigned long long)mb) - 1u;
        uint32_t base = 0;
        if (lane == leader) base = atomicAdd(&cnt[1 + par], (uint32_t)__popcll(mb));
        base = (uint32_t)__shfl((int)base, (int)leader);
        if (surv) {
          uint32_t off = (uint32_t)__popcll(mb & ((1ull << lane) - 1ull));
          astore(&frNxt[base + off], v);
        }
      }
    }
    gbar_light(bc, bk);
    flen = aload(&cnt[1 + par]);
    uint32_t* t2 = frCur; frCur = frNxt; frNxt = t2;
    if (flen == 0) break;
  }

  // ---- P6: cluster assignment (gather, atomic-free) ----
  // mis was only astore'd since the last invalidate -> plain reads in the
  // scan fetch fresh values; scan ends with FULL (publishes idpos).
  uint32_t M = grid_exscan(N, [=](uint32_t i) { return mis[i] ? 1u : 0u; },
                           idpos, bsum, bc, bk);
  for (uint32_t v = tid; v < N; v += NTOT) {
    if (mis[v]) {
      r2ip[rank[v]] = idpos[v];
      blist[idpos[v]] = v;  // MIS nodes in id order
      atomicMax(&cnt[4], rank[v]);
    }
  }
  gbar(bc, bk);  // FULL: publish r2ip/blist
  // clus computation + bitmap zeroing folded into ONE phase (saves a fence).
  uint64_t M2 = (uint64_t)M * (uint64_t)M;
  uint32_t nwords = (uint32_t)((M2 + 31) >> 5);
  uint32_t* bitmap = dyn;
  uint32_t* wpre = bitmap + nwords;
  bool wsok = ((uint64_t)(dyn - w) + 2ull * nwords) <= (uint64_t)wcap;
  {
    uint32_t maxrank = cnt[4];
    for (uint32_t v = tid; v < N; v += NTOT) {
      uint32_t mv = mis[v] ? rank[v] : INF32;
      uint32_t s0 = sc[65536u + v] - N;
      uint32_t s1 = (v + 1 < N) ? (sc[65536u + v + 1] - N) : E;
      uint32_t j = s0;
      for (; j + 4u <= s1; j += 4u) {  // mis[u] = rank+1: single indep gather
        uint32_t m0 = mis[adj[j]], m1 = mis[adj[j+1]];
        uint32_t m2 = mis[adj[j+2]], m3 = mis[adj[j+3]];
        if (m0) { uint32_t ru = m0 - 1u; if (ru < mv) mv = ru; }
        if (m1) { uint32_t ru = m1 - 1u; if (ru < mv) mv = ru; }
        if (m2) { uint32_t ru = m2 - 1u; if (ru < mv) mv = ru; }
        if (m3) { uint32_t ru = m3 - 1u; if (ru < mv) mv = ru; }
      }
      for (; j < s1; ++j) {
        uint32_t m0 = mis[adj[j]];
        if (m0) { uint32_t ru = m0 - 1u; if (ru < mv) mv = ru; }
      }
      clus[v] = r2ip[(mv == INF32) ? maxrank : mv];  // orphan: clamped OOB gather
    }
  }
  if (wsok) {
    for (uint32_t i = tid; i < nwords; i += NTOT) astore(&bitmap[i], 0u);
  }
  gbar(bc, bk);  // FULL: publish clus (bitmap zeros are memory-side already)

  // ---- P7: coarse edges (unique off-diagonal pairs, lexicographic) ----
  // Mirror halving: half-edge (r,c) -> coarse (a,b) AND (b,a); identical key
  // set and attr sums as full-list processing, half the reads and gathers.
  if (wsok) {
    for (uint32_t e = tid; e < EH; e += NTOT) {
      uint32_t a = clus[(uint32_t)rowA[e]], b = clus[(uint32_t)colA[e]];
      if (a != b) {
        uint32_t k1 = a * M + b;
        uint32_t k2 = b * M + a;
        atomicOr(&bitmap[k1 >> 5], 1u << (k1 & 31u));
        atomicOr(&bitmap[k2 >> 5], 1u << (k2 & 31u));
      }
    }
    for (uint32_t e = (EH << 1) + tid; e < E; e += NTOT) {  // odd-E tail
      uint32_t a = clus[(uint32_t)rowA[e]], b = clus[(uint32_t)colA[e]];
      if (a != b) {
        uint32_t key = a * M + b;
        atomicOr(&bitmap[key >> 5], 1u << (key & 31u));
      }
    }
    gbar_light(bc, bk);  // bitmap RMWs memory-side; no stale L2 lines exist
    uint32_t nk = grid_exscan(
        nwords, [=](uint32_t i) { return (uint32_t)__popc(bitmap[i]); }, wpre,
        bsum, bc, bk);   // ends FULL: publishes wpre
    uint64_t oEI = (uint64_t)M * 128ull;
    uint64_t oEA = oEI + 2ull * nk;
    uint64_t oCL = oEA + nk;
    uint64_t oMIS = oCL + N;
    uint64_t oSC = oMIS + N;
    bool fits = (oSC + N) <= (uint64_t)out_size;
    if (fits) {
      // attr zeros via astore (memory-side) so the following atomicAdds read
      // true zeros with only a LIGHT barrier between.
      for (uint32_t i = tid; i < nk; i += NTOT)
        astore((uint32_t*)&out[oEA + i], 0u);
      for (uint32_t wd = tid; wd < nwords; wd += NTOT) {
        uint32_t bits = bitmap[wd];
        uint32_t slot = wpre[wd];
        while (bits) {
          uint32_t bpos = (uint32_t)__ffs(bits) - 1u;
          bits &= bits - 1u;
          uint32_t key = (wd << 5) + bpos;
          uint32_t aa = key / M;
          uint32_t bb = key - aa * M;
          out[oEI + slot] = (float)aa;
          out[oEI + (uint64_t)nk + slot] = (float)bb;
          slot++;
        }
      }
      gbar_light(bc, bk);  // order attr-zeros before atomicAdds; emit stores
                           // are byte-masked plain writes, flushed at kernel end
      for (uint32_t e = tid; e < EH; e += NTOT) {
        uint32_t a = clus[(uint32_t)rowA[e]], b = clus[(uint32_t)colA[e]];
        if (a != b) {
          float wv = eattr[e];   // eattr[e + EH] == eattr[e] by construction
          uint32_t k1 = a * M + b;
          uint32_t wd1 = k1 >> 5, bit1 = k1 & 31u;
          uint32_t s1_ = wpre[wd1] + (uint32_t)__popc(bitmap[wd1] & ((1u << bit1) - 1u));
          atomicAdd(&out[oEA + s1_], wv);
          uint32_t k2 = b * M + a;
          uint32_t wd2 = k2 >> 5, bit2 = k2 & 31u;
          uint32_t s2_ = wpre[wd2] + (uint32_t)__popc(bitmap[wd2] & ((1u << bit2) - 1u));
          atomicAdd(&out[oEA + s2_], wv);
        }
      }
      for (uint32_t e = (EH << 1) + tid; e < E; e += NTOT) {  // odd-E tail
        uint32_t a = clus[(uint32_t)rowA[e]], b = clus[(uint32_t)colA[e]];
        if (a != b) {
          uint32_t key = a * M + b;
          uint32_t wd = key >> 5, bit = key & 31u;
          uint32_t slot = wpre[wd] + (uint32_t)__popc(bitmap[wd] & ((1u << bit) - 1u));
          atomicAdd(&out[oEA + slot], eattr[e]);
        }
      }
      // x gather (float4-vectorized), MIS rows in id order
      const float4* x4 = (const float4*)x;
      float4* o4 = (float4*)out;
      uint32_t xtot = M * 32u;
      for (uint32_t i = tid; i < xtot; i += NTOT) {
        uint32_t row = i >> 5;
        o4[i] = x4[((uint64_t)blist[row] << 5) + (i & 31u)];
      }
      for (uint32_t v = tid; v < N; v += NTOT) {
        out[oCL + v] = (float)clus[v];
        out[oMIS + v] = mis[v] ? 1.0f : 0.0f;
        out[oSC + v] = score[v];
      }
    }
  }
}

extern "C" void kernel_launch(void* const* d_in, const int* in_sizes, int n_in,
                              void* d_out, int out_size, void* d_ws, size_t ws_size,
                              hipStream_t stream) {
  (void)n_in;
  const float* x = (const float*)d_in[0];
  const int* eidx = (const int*)d_in[1];
  const float* eattr = (const float*)d_in[2];
  const float* score = (const float*)d_in[3];
  float* out = (float*)d_out;
  uint32_t* w = (uint32_t*)d_ws;
  int N = in_sizes[3];
  int E = in_sizes[2];
  long long osz = (long long)out_size;
  unsigned long long wcap = (unsigned long long)(ws_size / 4);
  void* args[] = {&x, &eidx, &eattr, &score, &out, &w, &N, &E, &osz, &wcap};
  hipLaunchCooperativeKernel((void*)kmis_kernel, dim3(NBLK), dim3(NTHR), args, 0,
                             stream);
}